// Round 2
// baseline (845.999 us; speedup 1.0000x reference)
//
#include <hip/hip_runtime.h>
#include <hip/hip_bf16.h>
#include <stdint.h>

#define HID 256
#define BM  64
#define KCH 32          // k per chunk
#define NCH 16          // 512 / 32 chunks
#define LDB 34          // Bs row stride in ushort (32 + 2 pad -> 17-dword stride, balanced banks)

typedef __bf16 bf16x8 __attribute__((ext_vector_type(8)));
typedef float  f32x4  __attribute__((ext_vector_type(4)));

__device__ __forceinline__ ushort f2bf(float x) {
    union { float f; uint32_t u; } v; v.f = x;
    uint32_t u = v.u;
    uint32_t r = u + 0x7fffu + ((u >> 16) & 1u);   // RNE
    return (ushort)(r >> 16);
}

// stream-convert fp32 table -> bf16 (coalesced both sides), 8 elems/thread
__global__ void conv_emb(const float* __restrict__ src, ushort* __restrict__ dst, int n8) {
    int t = blockIdx.x * 256 + threadIdx.x;
    if (t >= n8) return;
    size_t base = (size_t)t * 8;
    float4 a = *reinterpret_cast<const float4*>(src + base);
    float4 b = *reinterpret_cast<const float4*>(src + base + 4);
    union { ushort s[8]; uint4 v; } u;
    u.s[0] = f2bf(a.x); u.s[1] = f2bf(a.y); u.s[2] = f2bf(a.z); u.s[3] = f2bf(a.w);
    u.s[4] = f2bf(b.x); u.s[5] = f2bf(b.y); u.s[6] = f2bf(b.z); u.s[7] = f2bf(b.w);
    *reinterpret_cast<uint4*>(dst + base) = u.v;
}

// W1[512][256] fp32 -> chunked-transposed bf16 Wt2: [chunk c][n 0..255][kk 0..31]
// so staging chunk c in lp_gemm is one contiguous 16 KB read.
__global__ void conv_w1(const float* __restrict__ W1, ushort* __restrict__ Wt2) {
    __shared__ ushort tr[32][33];
    const int bn = blockIdx.x & 7;    // n-tile 0..7
    const int bk = blockIdx.x >> 3;   // k-tile (== chunk) 0..15
    const int t  = threadIdx.x;
    #pragma unroll
    for (int i = 0; i < 4; ++i) {
        int e = t + 256 * i; int r = e >> 5, cc = e & 31;
        tr[cc][r] = f2bf(W1[(size_t)(bk * 32 + r) * HID + bn * 32 + cc]);
    }
    __syncthreads();
    #pragma unroll
    for (int i = 0; i < 4; ++i) {
        int e = t + 256 * i; int rn = e >> 5, ck = e & 31;
        Wt2[((size_t)bk * HID + bn * 32 + rn) * 32 + ck] = tr[rn][ck];
    }
}

template<int USEBF, int USEWT>
__global__ __launch_bounds__(256, 3)
void lp_gemm(const float* __restrict__ es32, const float* __restrict__ ed32,
             const ushort* __restrict__ esb, const ushort* __restrict__ edb,
             const int* __restrict__ eli, const ushort* __restrict__ Wt2,
             const float* __restrict__ W1,
             const float* __restrict__ b1, const float* __restrict__ W2,
             const float* __restrict__ b2,
             float* __restrict__ out, int E) {
    __shared__ __align__(16) ushort Bs[2][HID * LDB];   // 34816 B
    __shared__ int   sIdx[2][BM];
    __shared__ float hred[4][BM];

    const int t    = threadIdx.x;
    const int e0   = blockIdx.x * BM;
    const int wave = t >> 6;
    const int lane = t & 63;
    const int q    = lane >> 4;
    const int cl   = lane & 15;

    if (t < 2 * BM) {
        int which = t >> 6, e = t & 63;
        int ge = e0 + e; if (ge > E - 1) ge = E - 1;
        sIdx[which][e] = eli[which * E + ge];
    }

    uint4 stg[4];
    auto loadB = [&](int c) {
        if (USEWT) {
            const uint4* src = reinterpret_cast<const uint4*>(Wt2 + (size_t)c * HID * KCH);
            #pragma unroll
            for (int i = 0; i < 4; ++i) stg[i] = src[t + 256 * i];
        } else {
            #pragma unroll
            for (int i = 0; i < 4; ++i) {
                int u = t + 256 * i;
                int n = u >> 2, k0 = (u & 3) * 8;
                union { ushort s[8]; uint4 v; } x;
                #pragma unroll
                for (int j = 0; j < 8; ++j)
                    x.s[j] = f2bf(W1[(size_t)(c * KCH + k0 + j) * HID + n]);
                stg[i] = x.v;
            }
        }
    };
    auto storeB = [&](int buf) {
        #pragma unroll
        for (int i = 0; i < 4; ++i) {
            int u = t + 256 * i;
            *reinterpret_cast<uint4*>(&Bs[buf][(u >> 2) * LDB + (u & 3) * 8]) = stg[i];
        }
    };

    // chunk 0 -> Bs[0]
    loadB(0); storeB(0);
    __syncthreads();

    int rs[4], rd[4];
    #pragma unroll
    for (int mi = 0; mi < 4; ++mi) {
        rs[mi] = sIdx[0][mi * 16 + cl];
        rd[mi] = sIdx[1][mi * 16 + cl];
    }

    auto loadA = [&](int c, bf16x8* af) {
        #pragma unroll
        for (int mi = 0; mi < 4; ++mi) {
            int row = (c < 8) ? rs[mi] : rd[mi];
            int kof = (c & 7) * KCH + q * 8;
            if (USEBF) {
                const ushort* p = ((c < 8) ? esb : edb) + (size_t)row * HID + kof;
                af[mi] = *reinterpret_cast<const bf16x8*>(p);
            } else {
                const float* p = ((c < 8) ? es32 : ed32) + (size_t)row * HID + kof;
                float4 a = *reinterpret_cast<const float4*>(p);
                float4 b = *reinterpret_cast<const float4*>(p + 4);
                union { ushort s[8]; bf16x8 v; } u;
                u.s[0] = f2bf(a.x); u.s[1] = f2bf(a.y); u.s[2] = f2bf(a.z); u.s[3] = f2bf(a.w);
                u.s[4] = f2bf(b.x); u.s[5] = f2bf(b.y); u.s[6] = f2bf(b.z); u.s[7] = f2bf(b.w);
                af[mi] = u.v;
            }
        }
    };

    f32x4 acc[4][4] = {};
    bf16x8 afc[4], afn[4];
    loadA(0, afc);

    #pragma unroll
    for (int c = 0; c < NCH; ++c) {
        const int cur = c & 1;
        if (c + 1 < NCH) { loadB(c + 1); loadA(c + 1, afn); }

        bf16x8 bfr[4];
        #pragma unroll
        for (int ni = 0; ni < 4; ++ni)
            bfr[ni] = *reinterpret_cast<const bf16x8*>(
                &Bs[cur][(wave * 64 + ni * 16 + cl) * LDB + q * 8]);
        #pragma unroll
        for (int mi = 0; mi < 4; ++mi)
            #pragma unroll
            for (int ni = 0; ni < 4; ++ni)
                acc[mi][ni] = __builtin_amdgcn_mfma_f32_16x16x32_bf16(
                    afc[mi], bfr[ni], acc[mi][ni], 0, 0, 0);

        if (c + 1 < NCH) {
            storeB(cur ^ 1);
            #pragma unroll
            for (int mi = 0; mi < 4; ++mi) afc[mi] = afn[mi];
            __syncthreads();
        }
    }

    // epilogue: h = relu(acc + b1); logit partial = h . W2 (fp32, fused)
    float b1v[4], w2v[4];
    #pragma unroll
    for (int ni = 0; ni < 4; ++ni) {
        int col = wave * 64 + ni * 16 + cl;
        b1v[ni] = b1[col];
        w2v[ni] = W2[col];
    }
    #pragma unroll
    for (int mi = 0; mi < 4; ++mi) {
        #pragma unroll
        for (int r = 0; r < 4; ++r) {
            float s = 0.f;
            #pragma unroll
            for (int ni = 0; ni < 4; ++ni) {
                float h = acc[mi][ni][r] + b1v[ni];
                h = fmaxf(h, 0.f);
                s += h * w2v[ni];
            }
            s += __shfl_xor(s, 1);
            s += __shfl_xor(s, 2);
            s += __shfl_xor(s, 4);
            s += __shfl_xor(s, 8);
            if (cl == 0) hred[wave][mi * 16 + q * 4 + r] = s;
        }
    }
    __syncthreads();
    if (t < BM) {
        int ge = e0 + t;
        if (ge < E)
            out[ge] = hred[0][t] + hred[1][t] + hred[2][t] + hred[3][t] + b2[0];
    }
}

extern "C" void kernel_launch(void* const* d_in, const int* in_sizes, int n_in,
                              void* d_out, int out_size, void* d_ws, size_t ws_size,
                              hipStream_t stream) {
    const float* emb_src = (const float*)d_in[0];
    const float* emb_dst = (const float*)d_in[1];
    const int*   eli     = (const int*)d_in[2];
    const float* W1      = (const float*)d_in[3];
    const float* b1      = (const float*)d_in[4];
    const float* W2      = (const float*)d_in[5];
    const float* b2      = (const float*)d_in[6];
    float*       out     = (float*)d_out;

    const int n0 = in_sizes[0], n1 = in_sizes[1];
    const int E  = in_sizes[2] / 2;

    const size_t wtB  = (size_t)NCH * HID * KCH * sizeof(ushort);     // 256 KB
    const size_t embB = ((size_t)n0 + (size_t)n1) * sizeof(ushort);   // ~102.4 MB
    const int useWt = ws_size >= wtB;
    const int useBf = ws_size >= wtB + embB;

    ushort* Wt2 = (ushort*)d_ws;
    ushort* esb = (ushort*)((char*)d_ws + wtB);
    ushort* edb = esb + n0;

    if (useWt)
        conv_w1<<<128, 256, 0, stream>>>(W1, Wt2);
    if (useBf) {
        conv_emb<<<(n0 / 8 + 255) / 256, 256, 0, stream>>>(emb_src, esb, n0 / 8);
        conv_emb<<<(n1 / 8 + 255) / 256, 256, 0, stream>>>(emb_dst, edb, n1 / 8);
    }

    const int nb = (E + BM - 1) / BM;
    if (useBf && useWt)
        lp_gemm<1, 1><<<nb, 256, 0, stream>>>(emb_src, emb_dst, esb, edb, eli, Wt2,
                                              W1, b1, W2, b2, out, E);
    else if (useWt)
        lp_gemm<0, 1><<<nb, 256, 0, stream>>>(emb_src, emb_dst, esb, edb, eli, Wt2,
                                              W1, b1, W2, b2, out, E);
    else
        lp_gemm<0, 0><<<nb, 256, 0, stream>>>(emb_src, emb_dst, esb, edb, eli, Wt2,
                                              W1, b1, W2, b2, out, E);
}

// Round 3
// 486.948 us; speedup vs baseline: 1.7374x; 1.7374x over previous
//
#include <hip/hip_runtime.h>
#include <hip/hip_bf16.h>
#include <stdint.h>

#define HID 256
#define BM  64
#define LDA 68   // As row stride in ushorts (34 dwords == 2 mod 32: minimal bank pressure)

typedef __bf16 bf16x8 __attribute__((ext_vector_type(8)));
typedef float  f32x4  __attribute__((ext_vector_type(4)));

__device__ __forceinline__ ushort f2bf(float x) {
    union { float f; uint32_t u; } v; v.f = x;
    uint32_t u = v.u;
    uint32_t r = u + 0x7fffu + ((u >> 16) & 1u);   // RNE
    return (ushort)(r >> 16);
}

// pack two fp32 -> one dword of two bf16 (a -> low16, b -> high16), round-half-up
__device__ __forceinline__ uint32_t pack2bf(float a, float b) {
    union { float f; uint32_t u; } ua, ub;
    ua.f = a; ub.f = b;
    return __builtin_amdgcn_perm(ub.u + 0x8000u, ua.u + 0x8000u, 0x07060302u);
}

// W1[512][256] fp32 -> Wt3 bf16, layout [c 0..7][n 0..255][kk 0..63]
// (chunk-major so lp_gemm's B-fragment reads are 1KB-coalesced, block-invariant)
__global__ void conv_w1(const float* __restrict__ W1, ushort* __restrict__ Wt3) {
    __shared__ ushort tr[32][33];
    const int bk = blockIdx.x >> 3;   // k-tile 0..15
    const int bn = blockIdx.x & 7;    // n-tile 0..7
    const int t  = threadIdx.x;
    #pragma unroll
    for (int i = 0; i < 4; ++i) {
        int e = t + 256 * i; int r = e >> 5, cc = e & 31;
        tr[cc][r] = f2bf(W1[(size_t)(bk * 32 + r) * HID + bn * 32 + cc]);
    }
    __syncthreads();
    #pragma unroll
    for (int i = 0; i < 4; ++i) {
        int e = t + 256 * i; int rn = e >> 5, ck = e & 31;
        int k = bk * 32 + ck; int c = k >> 6; int kk = k & 63;
        Wt3[((size_t)c * HID + bn * 32 + rn) * 64 + kk] = tr[rn][ck];
    }
}

template<int USEWT>
__global__ __launch_bounds__(256, 3)
void lp_gemm(const float* __restrict__ es, const float* __restrict__ ed,
             const int* __restrict__ eli,
             const ushort* __restrict__ Wt3, const float* __restrict__ W1,
             const float* __restrict__ b1, const float* __restrict__ W2,
             const float* __restrict__ b2,
             float* __restrict__ out, int E) {
    __shared__ __align__(16) ushort As[2][BM * LDA];   // 2 x 8704 B
    __shared__ int   sIdx[2][BM];
    __shared__ float hred[4][BM];

    const int t    = threadIdx.x;
    const int e0   = blockIdx.x * BM;
    const int wave = t >> 6;
    const int lane = t & 63;
    const int q    = lane >> 4;
    const int cl   = lane & 15;

    if (t < 2 * BM) {
        int which = t >> 6, e = t & 63;
        int ge = e0 + e; if (ge > E - 1) ge = E - 1;
        sIdx[which][e] = eli[which * E + ge];
    }
    __syncthreads();

    // gather coords: i in {0,1}: thread covers (row ge_[i], 32B-span go_[i])
    int ge_[2], go_[2], rsrc[2], rdst[2];
    #pragma unroll
    for (int i = 0; i < 2; ++i) {
        int c2 = t + 256 * i;
        ge_[i] = c2 >> 3; go_[i] = c2 & 7;
        rsrc[i] = sIdx[0][ge_[i]];
        rdst[i] = sIdx[1][ge_[i]];
    }

    float4 g0[2], g1[2];
    auto gather = [&](int c) {
        const float* tab = (c < 4) ? es : ed;
        #pragma unroll
        for (int i = 0; i < 2; ++i) {
            int row = (c < 4) ? rsrc[i] : rdst[i];
            const float* p = tab + (size_t)row * HID + (c & 3) * 64 + go_[i] * 8;
            g0[i] = *reinterpret_cast<const float4*>(p);
            g1[i] = *reinterpret_cast<const float4*>(p + 4);
        }
    };
    auto cvstore = [&](int buf) {
        #pragma unroll
        for (int i = 0; i < 2; ++i) {
            uint4 v;
            v.x = pack2bf(g0[i].x, g0[i].y);
            v.y = pack2bf(g0[i].z, g0[i].w);
            v.z = pack2bf(g1[i].x, g1[i].y);
            v.w = pack2bf(g1[i].z, g1[i].w);
            *reinterpret_cast<uint4*>(&As[buf][ge_[i] * LDA + go_[i] * 8]) = v;
        }
    };

    gather(0);
    cvstore(0);
    __syncthreads();

    f32x4 acc[4][4] = {};

    #pragma unroll
    for (int c = 0; c < 8; ++c) {
        const int cur = c & 1;
        if (c < 7) gather(c + 1);      // loads in flight across the MFMA block

        #pragma unroll
        for (int ks = 0; ks < 2; ++ks) {
            bf16x8 af[4], bfr[4];
            #pragma unroll
            for (int mi = 0; mi < 4; ++mi)
                af[mi] = *reinterpret_cast<const bf16x8*>(
                    &As[cur][(mi * 16 + cl) * LDA + ks * 32 + q * 8]);
            #pragma unroll
            for (int ni = 0; ni < 4; ++ni) {
                int n = wave * 64 + ni * 16 + cl;
                if (USEWT) {
                    bfr[ni] = *reinterpret_cast<const bf16x8*>(
                        Wt3 + ((size_t)c * HID + n) * 64 + ks * 32 + q * 8);
                } else {
                    union { ushort s[8]; bf16x8 v; } u;
                    #pragma unroll
                    for (int j = 0; j < 8; ++j)
                        u.s[j] = f2bf(W1[(size_t)(c * 64 + ks * 32 + q * 8 + j) * HID + n]);
                    bfr[ni] = u.v;
                }
            }
            #pragma unroll
            for (int mi = 0; mi < 4; ++mi)
                #pragma unroll
                for (int ni = 0; ni < 4; ++ni)
                    acc[mi][ni] = __builtin_amdgcn_mfma_f32_16x16x32_bf16(
                        af[mi], bfr[ni], acc[mi][ni], 0, 0, 0);
        }

        if (c < 7) {
            cvstore(cur ^ 1);
            __syncthreads();
        }
    }

    // epilogue: h = relu(acc + b1); logit partial = h . W2 (fp32, fused)
    float b1v[4], w2v[4];
    #pragma unroll
    for (int ni = 0; ni < 4; ++ni) {
        int col = wave * 64 + ni * 16 + cl;
        b1v[ni] = b1[col];
        w2v[ni] = W2[col];
    }
    #pragma unroll
    for (int mi = 0; mi < 4; ++mi) {
        #pragma unroll
        for (int r = 0; r < 4; ++r) {
            float s = 0.f;
            #pragma unroll
            for (int ni = 0; ni < 4; ++ni) {
                float h = acc[mi][ni][r] + b1v[ni];
                h = fmaxf(h, 0.f);
                s += h * w2v[ni];
            }
            s += __shfl_xor(s, 1);
            s += __shfl_xor(s, 2);
            s += __shfl_xor(s, 4);
            s += __shfl_xor(s, 8);
            if (cl == 0) hred[wave][mi * 16 + q * 4 + r] = s;
        }
    }
    __syncthreads();
    if (t < BM) {
        int ge = e0 + t;
        if (ge < E)
            out[ge] = hred[0][t] + hred[1][t] + hred[2][t] + hred[3][t] + b2[0];
    }
}

extern "C" void kernel_launch(void* const* d_in, const int* in_sizes, int n_in,
                              void* d_out, int out_size, void* d_ws, size_t ws_size,
                              hipStream_t stream) {
    const float* emb_src = (const float*)d_in[0];
    const float* emb_dst = (const float*)d_in[1];
    const int*   eli     = (const int*)d_in[2];
    const float* W1      = (const float*)d_in[3];
    const float* b1      = (const float*)d_in[4];
    const float* W2      = (const float*)d_in[5];
    const float* b2      = (const float*)d_in[6];
    float*       out     = (float*)d_out;

    const int E = in_sizes[2] / 2;

    const size_t wtB = (size_t)8 * HID * 64 * sizeof(ushort);   // 256 KB
    const int useWt = ws_size >= wtB;
    ushort* Wt3 = (ushort*)d_ws;

    if (useWt)
        conv_w1<<<128, 256, 0, stream>>>(W1, Wt3);

    const int nb = (E + BM - 1) / BM;
    if (useWt)
        lp_gemm<1><<<nb, 256, 0, stream>>>(emb_src, emb_dst, eli, Wt3, W1,
                                           b1, W2, b2, out, E);
    else
        lp_gemm<0><<<nb, 256, 0, stream>>>(emb_src, emb_dst, eli, Wt3, W1,
                                           b1, W2, b2, out, E);
}

// Round 4
// 478.439 us; speedup vs baseline: 1.7682x; 1.0178x over previous
//
#include <hip/hip_runtime.h>
#include <hip/hip_bf16.h>
#include <stdint.h>

#define HID 256
#define BM  64
#define LDA 132  // As row stride in ushorts (66 dwords == 2 mod 32; same zero-conflict class as R3)

typedef __bf16 bf16x8 __attribute__((ext_vector_type(8)));
typedef float  f32x4  __attribute__((ext_vector_type(4)));

__device__ __forceinline__ ushort f2bf(float x) {
    union { float f; uint32_t u; } v; v.f = x;
    uint32_t u = v.u;
    uint32_t r = u + 0x7fffu + ((u >> 16) & 1u);   // RNE
    return (ushort)(r >> 16);
}

// pack two fp32 -> one dword of two bf16 (round-half-up via +0x8000, then take high16s)
__device__ __forceinline__ uint32_t pack2bf(float a, float b) {
    union { float f; uint32_t u; } ua, ub;
    ua.f = a; ub.f = b;
    return __builtin_amdgcn_perm(ub.u + 0x8000u, ua.u + 0x8000u, 0x07060302u);
}

// W1[512][256] fp32 -> Wt3 bf16, layout [c 0..7][n 0..255][kk 0..63]
__global__ void conv_w1(const float* __restrict__ W1, ushort* __restrict__ Wt3) {
    __shared__ ushort tr[32][33];
    const int bk = blockIdx.x >> 3;   // k-tile 0..15
    const int bn = blockIdx.x & 7;    // n-tile 0..7
    const int t  = threadIdx.x;
    #pragma unroll
    for (int i = 0; i < 4; ++i) {
        int e = t + 256 * i; int r = e >> 5, cc = e & 31;
        tr[cc][r] = f2bf(W1[(size_t)(bk * 32 + r) * HID + bn * 32 + cc]);
    }
    __syncthreads();
    #pragma unroll
    for (int i = 0; i < 4; ++i) {
        int e = t + 256 * i; int rn = e >> 5, ck = e & 31;
        int k = bk * 32 + ck; int c = k >> 6; int kk = k & 63;
        Wt3[((size_t)c * HID + bn * 32 + rn) * 64 + kk] = tr[rn][ck];
    }
}

template<int USEWT>
__global__ __launch_bounds__(256, 3)
void lp_gemm(const float* __restrict__ es, const float* __restrict__ ed,
             const int* __restrict__ eli,
             const ushort* __restrict__ Wt3, const float* __restrict__ W1,
             const float* __restrict__ b1, const float* __restrict__ W2,
             const float* __restrict__ b2,
             float* __restrict__ out, int E) {
    // double-buffered A slab: 64 rows x 128 k (bf16), per 128-k interval
    __shared__ __align__(16) ushort As[2][BM * LDA];   // 2 x 16896 B
    __shared__ int   sIdx[2][BM];
    __shared__ float hred[4][BM];

    const int t    = threadIdx.x;
    const int e0   = blockIdx.x * BM;
    const int wave = t >> 6;
    const int lane = t & 63;
    const int q    = lane >> 4;
    const int cl   = lane & 15;

    if (t < 2 * BM) {
        int which = t >> 6, e = t & 63;
        int ge = e0 + e; if (ge > E - 1) ge = E - 1;
        sIdx[which][e] = eli[which * E + ge];
    }
    __syncthreads();

    // gather geometry: thread covers k-span off8*8 (floats) of rows r_i = (t>>4)+16i
    const int off8 = t & 15;
    int rows_[4], rowd_[4], era_[4];
    #pragma unroll
    for (int i = 0; i < 4; ++i) {
        int e = (t >> 4) + 16 * i;
        era_[i]  = e;
        rows_[i] = sIdx[0][e];
        rowd_[i] = sIdx[1][e];
    }

    float4 g0[4], g1[4];
    // interval p covers virtual k in [p*128, p*128+128): p<2 -> src table, p>=2 -> dst
    auto gather = [&](int p) {
        const float* tab = (p < 2) ? es : ed;
        const int coloff = (p & 1) * 128 + off8 * 8;
        #pragma unroll
        for (int i = 0; i < 4; ++i) {
            int row = (p < 2) ? rows_[i] : rowd_[i];
            const float* pp = tab + (size_t)row * HID + coloff;
            g0[i] = *reinterpret_cast<const float4*>(pp);
            g1[i] = *reinterpret_cast<const float4*>(pp + 4);
        }
    };
    auto cvstore = [&](int buf) {
        #pragma unroll
        for (int i = 0; i < 4; ++i) {
            uint4 v;
            v.x = pack2bf(g0[i].x, g0[i].y);
            v.y = pack2bf(g0[i].z, g0[i].w);
            v.z = pack2bf(g1[i].x, g1[i].y);
            v.w = pack2bf(g1[i].z, g1[i].w);
            *reinterpret_cast<uint4*>(&As[buf][era_[i] * LDA + off8 * 8]) = v;
        }
    };

    gather(0);
    cvstore(0);
    __syncthreads();

    f32x4 acc[4][4] = {};

    #pragma unroll
    for (int p = 0; p < 4; ++p) {
        const int cur = p & 1;
        if (p < 3) gather(p + 1);   // one register batch in flight across the MFMA block

        #pragma unroll
        for (int ks = 0; ks < 4; ++ks) {          // 4 x K=32 inside the interval, no syncs
            bf16x8 af[4], bfr[4];
            #pragma unroll
            for (int mi = 0; mi < 4; ++mi)
                af[mi] = *reinterpret_cast<const bf16x8*>(
                    &As[cur][(mi * 16 + cl) * LDA + ks * 32 + q * 8]);
            const int c = 2 * p + (ks >> 1);      // 64-k chunk index in Wt3
            const int kk = (ks & 1) * 32 + q * 8;
            #pragma unroll
            for (int ni = 0; ni < 4; ++ni) {
                int n = wave * 64 + ni * 16 + cl;
                if (USEWT) {
                    bfr[ni] = *reinterpret_cast<const bf16x8*>(
                        Wt3 + ((size_t)c * HID + n) * 64 + kk);
                } else {
                    union { ushort s[8]; bf16x8 v; } u;
                    #pragma unroll
                    for (int j = 0; j < 8; ++j)
                        u.s[j] = f2bf(W1[(size_t)(c * 64 + kk + j) * HID + n]);
                    bfr[ni] = u.v;
                }
            }
            #pragma unroll
            for (int mi = 0; mi < 4; ++mi)
                #pragma unroll
                for (int ni = 0; ni < 4; ++ni)
                    acc[mi][ni] = __builtin_amdgcn_mfma_f32_16x16x32_bf16(
                        af[mi], bfr[ni], acc[mi][ni], 0, 0, 0);
        }

        if (p < 3) {
            cvstore(cur ^ 1);
            __syncthreads();
        }
    }

    // epilogue: h = relu(acc + b1); logit partial = h . W2 (fp32, fused)
    float b1v[4], w2v[4];
    #pragma unroll
    for (int ni = 0; ni < 4; ++ni) {
        int col = wave * 64 + ni * 16 + cl;
        b1v[ni] = b1[col];
        w2v[ni] = W2[col];
    }
    #pragma unroll
    for (int mi = 0; mi < 4; ++mi) {
        #pragma unroll
        for (int r = 0; r < 4; ++r) {
            float s = 0.f;
            #pragma unroll
            for (int ni = 0; ni < 4; ++ni) {
                float h = acc[mi][ni][r] + b1v[ni];
                h = fmaxf(h, 0.f);
                s += h * w2v[ni];
            }
            s += __shfl_xor(s, 1);
            s += __shfl_xor(s, 2);
            s += __shfl_xor(s, 4);
            s += __shfl_xor(s, 8);
            if (cl == 0) hred[wave][mi * 16 + q * 4 + r] = s;
        }
    }
    __syncthreads();
    if (t < BM) {
        int ge = e0 + t;
        if (ge < E)
            out[ge] = hred[0][t] + hred[1][t] + hred[2][t] + hred[3][t] + b2[0];
    }
}

extern "C" void kernel_launch(void* const* d_in, const int* in_sizes, int n_in,
                              void* d_out, int out_size, void* d_ws, size_t ws_size,
                              hipStream_t stream) {
    const float* emb_src = (const float*)d_in[0];
    const float* emb_dst = (const float*)d_in[1];
    const int*   eli     = (const int*)d_in[2];
    const float* W1      = (const float*)d_in[3];
    const float* b1      = (const float*)d_in[4];
    const float* W2      = (const float*)d_in[5];
    const float* b2      = (const float*)d_in[6];
    float*       out     = (float*)d_out;

    const int E = in_sizes[2] / 2;

    const size_t wtB = (size_t)8 * HID * 64 * sizeof(ushort);   // 256 KB
    const int useWt = ws_size >= wtB;
    ushort* Wt3 = (ushort*)d_ws;

    if (useWt)
        conv_w1<<<128, 256, 0, stream>>>(W1, Wt3);

    const int nb = (E + BM - 1) / BM;
    if (useWt)
        lp_gemm<1><<<nb, 256, 0, stream>>>(emb_src, emb_dst, eli, Wt3, W1,
                                           b1, W2, b2, out, E);
    else
        lp_gemm<0><<<nb, 256, 0, stream>>>(emb_src, emb_dst, eli, Wt3, W1,
                                           b1, W2, b2, out, E);
}

// Round 5
// 362.338 us; speedup vs baseline: 2.3348x; 1.3204x over previous
//
#include <hip/hip_runtime.h>
#include <hip/hip_bf16.h>
#include <stdint.h>

#define HID 256
#define BM  64
#define LDA 68    // As row stride in ushorts (34 dwords == 2 mod 32: measured zero-conflict in R3)
#define LDC 264   // Cs row stride in ushorts (132 dwords)

typedef __bf16 bf16x8 __attribute__((ext_vector_type(8)));
typedef float  f32x4  __attribute__((ext_vector_type(4)));

__device__ __forceinline__ ushort f2bf(float x) {
    union { float f; uint32_t u; } v; v.f = x;
    uint32_t u = v.u;
    uint32_t r = u + 0x7fffu + ((u >> 16) & 1u);   // RNE
    return (ushort)(r >> 16);
}

__device__ __forceinline__ uint32_t pack2bf(float a, float b) {
    union { float f; uint32_t u; } ua, ub;
    ua.f = a; ub.f = b;
    return __builtin_amdgcn_perm(ub.u + 0x8000u, ua.u + 0x8000u, 0x07060302u);
}

__device__ __forceinline__ float uaf(uint32_t x) {
    union { uint32_t u; float f; } c; c.u = x; return c.f;
}

// W1[512][256] fp32 -> Wt3 bf16, layout [c 0..7][n 0..255][kk 0..63]
__global__ void conv_w1(const float* __restrict__ W1, ushort* __restrict__ Wt3) {
    __shared__ ushort tr[32][33];
    const int bk = blockIdx.x >> 3;   // k-tile 0..15
    const int bn = blockIdx.x & 7;    // n-tile 0..7
    const int t  = threadIdx.x;
    #pragma unroll
    for (int i = 0; i < 4; ++i) {
        int e = t + 256 * i; int r = e >> 5, cc = e & 31;
        tr[cc][r] = f2bf(W1[(size_t)(bk * 32 + r) * HID + bn * 32 + cc]);
    }
    __syncthreads();
    #pragma unroll
    for (int i = 0; i < 4; ++i) {
        int e = t + 256 * i; int rn = e >> 5, ck = e & 31;
        int k = bk * 32 + ck; int c = k >> 6; int kk = k & 63;
        Wt3[((size_t)c * HID + bn * 32 + rn) * 64 + kk] = tr[rn][ck];
    }
}

// -------- phase 1: dense per-node GEMM  u = emb @ W1half  (bf16 out) --------
// grid: nb0 blocks for table 0 (emb_src @ W1[:256]), nb1 for table 1.
__global__ __launch_bounds__(256, 3)
void node_gemm(const float* __restrict__ emb0, const float* __restrict__ emb1,
               const ushort* __restrict__ Wt3,
               ushort* __restrict__ u0, ushort* __restrict__ u1,
               int n0, int n1, int nb0) {
    __shared__ union {
        ushort As[2][BM * LDA];   // 17408 B
        ushort Cs[BM * LDC];      // 33792 B
    } sm;

    const int t    = threadIdx.x;
    const int tb   = (blockIdx.x >= nb0) ? 1 : 0;
    const int bloc = blockIdx.x - tb * nb0;
    const float*  emb = tb ? emb1 : emb0;
    ushort*       uo  = tb ? u1 : u0;
    const int     n   = tb ? n1 : n0;
    const int     e0  = bloc * BM;

    const int wave = t >> 6, lane = t & 63, q = lane >> 4, cl = lane & 15;

    // staging geometry: thread covers 16 consecutive floats of one row
    const int rr = t >> 2, ss = (t & 3) * 16;
    int grow = e0 + rr; if (grow > n - 1) grow = n - 1;
    const float* abase = emb + (size_t)grow * HID + ss;

    float4 g[4];
    auto gather = [&](int c) {
        const float4* p = reinterpret_cast<const float4*>(abase + c * 64);
        #pragma unroll
        for (int i = 0; i < 4; ++i) g[i] = p[i];
    };
    auto cvstore = [&](int buf) {
        uint4 v0, v1;
        v0.x = pack2bf(g[0].x, g[0].y); v0.y = pack2bf(g[0].z, g[0].w);
        v0.z = pack2bf(g[1].x, g[1].y); v0.w = pack2bf(g[1].z, g[1].w);
        v1.x = pack2bf(g[2].x, g[2].y); v1.y = pack2bf(g[2].z, g[2].w);
        v1.z = pack2bf(g[3].x, g[3].y); v1.w = pack2bf(g[3].z, g[3].w);
        *reinterpret_cast<uint4*>(&sm.As[buf][rr * LDA + ss])     = v0;
        *reinterpret_cast<uint4*>(&sm.As[buf][rr * LDA + ss + 8]) = v1;
    };

    gather(0); cvstore(0);
    __syncthreads();

    f32x4 acc[4][4] = {};

    #pragma unroll
    for (int c = 0; c < 4; ++c) {
        const int cur = c & 1;
        if (c < 3) gather(c + 1);
        #pragma unroll
        for (int ks = 0; ks < 2; ++ks) {
            bf16x8 af[4], bfr[4];
            #pragma unroll
            for (int mi = 0; mi < 4; ++mi)
                af[mi] = *reinterpret_cast<const bf16x8*>(
                    &sm.As[cur][(mi * 16 + cl) * LDA + ks * 32 + q * 8]);
            const int cg = tb * 4 + c;
            #pragma unroll
            for (int ni = 0; ni < 4; ++ni)
                bfr[ni] = *reinterpret_cast<const bf16x8*>(
                    Wt3 + ((size_t)cg * HID + wave * 64 + ni * 16 + cl) * 64 + ks * 32 + q * 8);
            #pragma unroll
            for (int mi = 0; mi < 4; ++mi)
                #pragma unroll
                for (int ni = 0; ni < 4; ++ni)
                    acc[mi][ni] = __builtin_amdgcn_mfma_f32_16x16x32_bf16(
                        af[mi], bfr[ni], acc[mi][ni], 0, 0, 0);
        }
        if (c < 3) { cvstore(cur ^ 1); __syncthreads(); }
    }

    __syncthreads();   // all As reads done before Cs overwrites the union
    #pragma unroll
    for (int mi = 0; mi < 4; ++mi)
        #pragma unroll
        for (int ni = 0; ni < 4; ++ni)
            #pragma unroll
            for (int r = 0; r < 4; ++r)
                sm.Cs[(mi * 16 + q * 4 + r) * LDC + wave * 64 + ni * 16 + cl] =
                    f2bf(acc[mi][ni][r]);
    __syncthreads();

    const int srow = t >> 2, scol = (t & 3) * 64;
    if (e0 + srow < n) {
        ushort* dst = uo + (size_t)(e0 + srow) * HID + scol;
        #pragma unroll
        for (int i = 0; i < 8; ++i) {
            uint4 w = *reinterpret_cast<const uint4*>(&sm.Cs[srow * LDC + scol + i * 8]);
            *reinterpret_cast<uint4*>(dst + i * 8) = w;
        }
    }
}

// -------- phase 2: per-edge  logit = relu(u[s]+v[d]+b1) . W2 + b2 --------
// One wave per edge batch of 8: lanes 0-31 read u[s] (16B each), lanes 32-63 read v[d].
__global__ __launch_bounds__(256, 4)
void lp_edge(const ushort* __restrict__ u, const ushort* __restrict__ v,
             const int* __restrict__ eli,
             const float* __restrict__ b1, const float* __restrict__ W2,
             const float* __restrict__ b2, float* __restrict__ out,
             int E, int nwaves) {
    const int lane = threadIdx.x & 63;
    const int half = lane >> 5, sub = lane & 31;
    const int wid  = blockIdx.x * (blockDim.x >> 6) + (threadIdx.x >> 6);

    float b1v[8], w2v[8];
    {
        const float4* p1 = reinterpret_cast<const float4*>(b1 + sub * 8);
        const float4* p2 = reinterpret_cast<const float4*>(W2 + sub * 8);
        float4 a = p1[0], b = p1[1], c = p2[0], d = p2[1];
        b1v[0]=a.x; b1v[1]=a.y; b1v[2]=a.z; b1v[3]=a.w;
        b1v[4]=b.x; b1v[5]=b.y; b1v[6]=b.z; b1v[7]=b.w;
        w2v[0]=c.x; w2v[1]=c.y; w2v[2]=c.z; w2v[3]=c.w;
        w2v[4]=d.x; w2v[5]=d.y; w2v[6]=d.z; w2v[7]=d.w;
    }
    const float bias2 = b2[0];
    const ushort* tab  = half ? v : u;
    const int*    idxp = eli + (size_t)half * E;

    for (int base = wid * 8; base < E; base += nwaves * 8) {
        uint4 g[8];
        #pragma unroll
        for (int j = 0; j < 8; ++j) {
            int e = base + j; if (e > E - 1) e = E - 1;
            int row = idxp[e];
            g[j] = *reinterpret_cast<const uint4*>(tab + (size_t)row * HID + sub * 8);
        }
        float res = 0.f;
        #pragma unroll
        for (int j = 0; j < 8; ++j) {
            uint32_t pd[4], gd[4] = { g[j].x, g[j].y, g[j].z, g[j].w };
            #pragma unroll
            for (int c = 0; c < 4; ++c) pd[c] = (uint32_t)__shfl_xor((int)gd[c], 32);
            float acc = 0.f;
            #pragma unroll
            for (int c = 0; c < 4; ++c) {
                float a0 = uaf(gd[c] << 16), a1 = uaf(gd[c] & 0xffff0000u);
                float o0 = uaf(pd[c] << 16), o1 = uaf(pd[c] & 0xffff0000u);
                float h0 = fmaxf(a0 + o0 + b1v[2 * c], 0.f);
                float h1 = fmaxf(a1 + o1 + b1v[2 * c + 1], 0.f);
                acc = fmaf(h0, w2v[2 * c], acc);
                acc = fmaf(h1, w2v[2 * c + 1], acc);
            }
            #pragma unroll
            for (int m = 1; m <= 16; m <<= 1) acc += __shfl_xor(acc, m);
            if (half == 0 && sub == j) res = acc + bias2;
        }
        int e = base + sub;
        if (half == 0 && sub < 8 && e < E) out[e] = res;
    }
}

// -------- fallback (R4 monolithic) if ws is too small --------
template<int USEWT>
__global__ __launch_bounds__(256, 3)
void lp_mono(const float* __restrict__ es, const float* __restrict__ ed,
             const int* __restrict__ eli,
             const ushort* __restrict__ Wt3, const float* __restrict__ W1,
             const float* __restrict__ b1, const float* __restrict__ W2,
             const float* __restrict__ b2,
             float* __restrict__ out, int E) {
    __shared__ __align__(16) ushort As[2][BM * LDA];
    __shared__ int   sIdx[2][BM];
    __shared__ float hred[4][BM];

    const int t = threadIdx.x, e0 = blockIdx.x * BM;
    const int wave = t >> 6, lane = t & 63, q = lane >> 4, cl = lane & 15;

    if (t < 2 * BM) {
        int which = t >> 6, e = t & 63;
        int ge = e0 + e; if (ge > E - 1) ge = E - 1;
        sIdx[which][e] = eli[which * E + ge];
    }
    __syncthreads();

    int ge_[2], go_[2], rsrc[2], rdst[2];
    #pragma unroll
    for (int i = 0; i < 2; ++i) {
        int c2 = t + 256 * i;
        ge_[i] = c2 >> 3; go_[i] = c2 & 7;
        rsrc[i] = sIdx[0][ge_[i]];
        rdst[i] = sIdx[1][ge_[i]];
    }
    float4 g0[2], g1[2];
    auto gather = [&](int c) {
        const float* tab = (c < 4) ? es : ed;
        #pragma unroll
        for (int i = 0; i < 2; ++i) {
            int row = (c < 4) ? rsrc[i] : rdst[i];
            const float* p = tab + (size_t)row * HID + (c & 3) * 64 + go_[i] * 8;
            g0[i] = *reinterpret_cast<const float4*>(p);
            g1[i] = *reinterpret_cast<const float4*>(p + 4);
        }
    };
    auto cvstore = [&](int buf) {
        #pragma unroll
        for (int i = 0; i < 2; ++i) {
            uint4 v;
            v.x = pack2bf(g0[i].x, g0[i].y); v.y = pack2bf(g0[i].z, g0[i].w);
            v.z = pack2bf(g1[i].x, g1[i].y); v.w = pack2bf(g1[i].z, g1[i].w);
            *reinterpret_cast<uint4*>(&As[buf][ge_[i] * LDA + go_[i] * 8]) = v;
        }
    };
    gather(0); cvstore(0); __syncthreads();
    f32x4 acc[4][4] = {};
    #pragma unroll
    for (int c = 0; c < 8; ++c) {
        const int cur = c & 1;
        if (c < 7) gather(c + 1);
        #pragma unroll
        for (int ks = 0; ks < 2; ++ks) {
            bf16x8 af[4], bfr[4];
            #pragma unroll
            for (int mi = 0; mi < 4; ++mi)
                af[mi] = *reinterpret_cast<const bf16x8*>(
                    &As[cur][(mi * 16 + cl) * LDA + ks * 32 + q * 8]);
            #pragma unroll
            for (int ni = 0; ni < 4; ++ni) {
                int n = wave * 64 + ni * 16 + cl;
                if (USEWT) {
                    bfr[ni] = *reinterpret_cast<const bf16x8*>(
                        Wt3 + ((size_t)c * HID + n) * 64 + ks * 32 + q * 8);
                } else {
                    union { ushort s[8]; bf16x8 v; } u;
                    #pragma unroll
                    for (int j = 0; j < 8; ++j)
                        u.s[j] = f2bf(W1[(size_t)(c * 64 + ks * 32 + q * 8 + j) * HID + n]);
                    bfr[ni] = u.v;
                }
            }
            #pragma unroll
            for (int mi = 0; mi < 4; ++mi)
                #pragma unroll
                for (int ni = 0; ni < 4; ++ni)
                    acc[mi][ni] = __builtin_amdgcn_mfma_f32_16x16x32_bf16(
                        af[mi], bfr[ni], acc[mi][ni], 0, 0, 0);
        }
        if (c < 7) { cvstore(cur ^ 1); __syncthreads(); }
    }
    float b1v[4], w2v[4];
    #pragma unroll
    for (int ni = 0; ni < 4; ++ni) {
        int col = wave * 64 + ni * 16 + cl;
        b1v[ni] = b1[col]; w2v[ni] = W2[col];
    }
    #pragma unroll
    for (int mi = 0; mi < 4; ++mi) {
        #pragma unroll
        for (int r = 0; r < 4; ++r) {
            float s = 0.f;
            #pragma unroll
            for (int ni = 0; ni < 4; ++ni) {
                float h = acc[mi][ni][r] + b1v[ni];
                h = fmaxf(h, 0.f);
                s += h * w2v[ni];
            }
            s += __shfl_xor(s, 1); s += __shfl_xor(s, 2);
            s += __shfl_xor(s, 4); s += __shfl_xor(s, 8);
            if (cl == 0) hred[wave][mi * 16 + q * 4 + r] = s;
        }
    }
    __syncthreads();
    if (t < BM) {
        int ge = e0 + t;
        if (ge < E)
            out[ge] = hred[0][t] + hred[1][t] + hred[2][t] + hred[3][t] + b2[0];
    }
}

extern "C" void kernel_launch(void* const* d_in, const int* in_sizes, int n_in,
                              void* d_out, int out_size, void* d_ws, size_t ws_size,
                              hipStream_t stream) {
    const float* emb_src = (const float*)d_in[0];
    const float* emb_dst = (const float*)d_in[1];
    const int*   eli     = (const int*)d_in[2];
    const float* W1      = (const float*)d_in[3];
    const float* b1      = (const float*)d_in[4];
    const float* W2      = (const float*)d_in[5];
    const float* b2      = (const float*)d_in[6];
    float*       out     = (float*)d_out;

    const int E   = in_sizes[2] / 2;
    const int n0n = in_sizes[0] / HID;
    const int n1n = in_sizes[1] / HID;

    const size_t wtB = (size_t)8 * HID * 64 * sizeof(ushort);    // 256 KB
    const size_t uB  = (size_t)n0n * HID * sizeof(ushort);
    const size_t vB  = (size_t)n1n * HID * sizeof(ushort);

    ushort* Wt3 = (ushort*)d_ws;
    ushort* u0  = (ushort*)((char*)d_ws + wtB);
    ushort* u1  = (ushort*)((char*)d_ws + wtB + uB);

    const int haveWt   = ws_size >= wtB;
    const int fullPath = ws_size >= wtB + uB + vB;

    if (haveWt)
        conv_w1<<<128, 256, 0, stream>>>(W1, Wt3);

    if (fullPath) {
        const int nb0 = (n0n + BM - 1) / BM;
        const int nb1 = (n1n + BM - 1) / BM;
        node_gemm<<<nb0 + nb1, 256, 0, stream>>>(emb_src, emb_dst, Wt3,
                                                 u0, u1, n0n, n1n, nb0);
        const int eb = 1024;
        lp_edge<<<eb, 256, 0, stream>>>(u0, u1, eli, b1, W2, b2, out, E, eb * 4);
    } else if (haveWt) {
        const int nb = (E + BM - 1) / BM;
        lp_mono<1><<<nb, 256, 0, stream>>>(emb_src, emb_dst, eli, Wt3, W1,
                                           b1, W2, b2, out, E);
    } else {
        const int nb = (E + BM - 1) / BM;
        lp_mono<0><<<nb, 256, 0, stream>>>(emb_src, emb_dst, eli, Wt3, W1,
                                           b1, W2, b2, out, E);
    }
}